// Round 4
// baseline (5071.047 us; speedup 1.0000x reference)
//
#include <hip/hip_runtime.h>
#include <stdint.h>

// Spiking neural network:
//   B=32 batches, S=1024 steps, I=256 inputs, H=512 hidden, O=256 outputs.
// Phase 0: wlat f32 -> f64 table (513 rows; row 512 is all zeros for padding).
// Phase 1: ic[B*S, H] (f64) = x[B*S, I] @ Win[I, H]   (feeds spike decisions)
// Phase 2: sequential scan per batch; f64 state; sparse lateral row-gather
//          with readfirstlane-scalar row bases + 2-deep load pipeline.
// Phase 3: out[B*S, O] (f32) = spikes @ Wout via bitmask-driven row sums.
//
// All decision-feeding arithmetic is f64 so spikes match an f64 numpy
// reference exactly; list-order / accumulator-grouping nondeterminism only
// perturbs f64 sums at ~1e-16.

#define BB 32
#define SS 1024
#define II 256
#define HH 512
#define OO 256
#define ZE (HH * HH)   // element offset of the all-zero row in wl64

// ---------------- Phase 0: wlat -> f64 table with zero row ----------------
__global__ __launch_bounds__(256) void wlat_to_f64(const float* __restrict__ wlat,
                                                   double* __restrict__ wl64) {
    const int i = blockIdx.x * 256 + threadIdx.x;
    const int total = (HH + 1) * HH;
    if (i < HH * HH) wl64[i] = (double)wlat[i];
    else if (i < total) wl64[i] = 0.0;
}

// ---------------- Phase 1: f64-accumulate tiled GEMM ----------------
#define TM 64
#define TN 64
#define TK 16

__global__ __launch_bounds__(256) void ic_gemm_f64(const float* __restrict__ x,
                                                   const float* __restrict__ win,
                                                   double* __restrict__ ic) {
    __shared__ float As[TK][TM + 4];
    __shared__ float Bs[TK][TN];
    const int tid = threadIdx.x;
    const int m0 = blockIdx.x * TM;
    const int n0 = blockIdx.y * TN;
    const int tx = tid & 15;
    const int ty = tid >> 4;

    double acc[4][4];
#pragma unroll
    for (int i = 0; i < 4; ++i)
#pragma unroll
        for (int j = 0; j < 4; ++j) acc[i][j] = 0.0;

    const int lr = tid >> 2;
    const int lq = tid & 3;
    const int br = tid >> 4;
    const int bq = tid & 15;

    for (int k0 = 0; k0 < II; k0 += TK) {
        float4 av = *(const float4*)(x + (size_t)(m0 + lr) * II + k0 + lq * 4);
        float4 bv = *(const float4*)(win + (size_t)(k0 + br) * HH + n0 + bq * 4);
        As[lq * 4 + 0][lr] = av.x;
        As[lq * 4 + 1][lr] = av.y;
        As[lq * 4 + 2][lr] = av.z;
        As[lq * 4 + 3][lr] = av.w;
        *(float4*)(&Bs[br][bq * 4]) = bv;
        __syncthreads();
#pragma unroll
        for (int kk = 0; kk < TK; ++kk) {
            float4 a = *(const float4*)(&As[kk][ty * 4]);
            float4 b = *(const float4*)(&Bs[kk][tx * 4]);
            const double a0 = (double)a.x, a1 = (double)a.y, a2 = (double)a.z, a3 = (double)a.w;
            const double b0 = (double)b.x, b1 = (double)b.y, b2 = (double)b.z, b3 = (double)b.w;
            acc[0][0] += a0 * b0; acc[0][1] += a0 * b1; acc[0][2] += a0 * b2; acc[0][3] += a0 * b3;
            acc[1][0] += a1 * b0; acc[1][1] += a1 * b1; acc[1][2] += a1 * b2; acc[1][3] += a1 * b3;
            acc[2][0] += a2 * b0; acc[2][1] += a2 * b1; acc[2][2] += a2 * b2; acc[2][3] += a2 * b3;
            acc[3][0] += a3 * b0; acc[3][1] += a3 * b1; acc[3][2] += a3 * b2; acc[3][3] += a3 * b3;
        }
        __syncthreads();
    }

#pragma unroll
    for (int i = 0; i < 4; ++i) {
        double* row = ic + (size_t)(m0 + ty * 4 + i) * HH + n0 + tx * 4;
#pragma unroll
        for (int j = 0; j < 4; ++j) row[j] = acc[i][j];
    }
}

// ---------------- Phase 2: sequential scan ----------------
// One block per batch, 1024 threads. Group A = tid<512 (neuron owners, even
// gather batches), group B = tid>=512 (odd gather batches). Active list holds
// element offsets h*512, zero-row (ZE) padded to a multiple of 8.
__global__ __launch_bounds__(1024) void snn_scan(const double* __restrict__ ic,
                                                 const double* __restrict__ wl64,
                                                 const float* __restrict__ thr,
                                                 uint64_t* __restrict__ masks) {
    __shared__ int s_act[2][520];
    __shared__ int s_nact[2];
    __shared__ double s_latB[HH];

    const int tid = threadIdx.x;
    const bool isA = (tid < HH);
    const int hp = isA ? tid : (tid - HH);
    const int b = blockIdx.x;
    const double* icb = ic + (size_t)b * SS * HH;
    uint64_t* mb = masks + (size_t)b * SS * 8;

    double mp = 0.0;
    int refrac = 0;
    double th = 0.0;
    if (isA) th = (double)thr[tid];
    if (tid == 0) { s_nact[0] = 0; s_nact[1] = 0; }
    if (tid < 520) { s_act[0][tid] = ZE; s_act[1][tid] = ZE; }
    __syncthreads();

    int cur = 0;
    for (int t = 0; t < SS; ++t) {
        const int nxt = cur ^ 1;

        // ---- phase 1: ic prefetch, re-pad next buffer, lateral gather ----
        double icv = 0.0;
        if (isA) icv = icb[(size_t)t * HH + tid];
        if (tid == HH) s_nact[nxt] = 0;
        // re-pad next act buffer: last read of this buffer was two barriers ago
        if (tid < 520) s_act[nxt][tid] = ZE;

        const int n = s_nact[cur];
        const int NB = (n + 7) >> 3;  // 8-wide batches (ZE-padded, maskless)
        const int* act = s_act[cur];

        double ac0 = 0.0, ac1 = 0.0, ac2 = 0.0, ac3 = 0.0,
               ac4 = 0.0, ac5 = 0.0, ac6 = 0.0, ac7 = 0.0;
        double va0, va1, va2, va3, va4, va5, va6, va7;
        double vb0, vb1, vb2, vb3, vb4, vb5, vb6, vb7;

#define LOADB(p0, p1, p2, p3, p4, p5, p6, p7, JJ) do {                         \
        const int* ap_ = act + ((JJ) << 3);                                    \
        const int4 qa_ = *(const int4*)ap_;                                    \
        const int4 qb_ = *(const int4*)(ap_ + 4);                              \
        p0 = (wl64 + (unsigned)__builtin_amdgcn_readfirstlane(qa_.x))[hp];     \
        p1 = (wl64 + (unsigned)__builtin_amdgcn_readfirstlane(qa_.y))[hp];     \
        p2 = (wl64 + (unsigned)__builtin_amdgcn_readfirstlane(qa_.z))[hp];     \
        p3 = (wl64 + (unsigned)__builtin_amdgcn_readfirstlane(qa_.w))[hp];     \
        p4 = (wl64 + (unsigned)__builtin_amdgcn_readfirstlane(qb_.x))[hp];     \
        p5 = (wl64 + (unsigned)__builtin_amdgcn_readfirstlane(qb_.y))[hp];     \
        p6 = (wl64 + (unsigned)__builtin_amdgcn_readfirstlane(qb_.z))[hp];     \
        p7 = (wl64 + (unsigned)__builtin_amdgcn_readfirstlane(qb_.w))[hp];     \
    } while (0)

#define ACCB(p0, p1, p2, p3, p4, p5, p6, p7) do {                              \
        ac0 += p0; ac1 += p1; ac2 += p2; ac3 += p3;                            \
        ac4 += p4; ac5 += p5; ac6 += p6; ac7 += p7; } while (0)

        int j = isA ? 0 : 1;  // A: even batches, B: odd batches
        if (j < NB) {
            LOADB(va0, va1, va2, va3, va4, va5, va6, va7, j);
            j += 2;
            while (j < NB) {
                LOADB(vb0, vb1, vb2, vb3, vb4, vb5, vb6, vb7, j);
                j += 2;
                ACCB(va0, va1, va2, va3, va4, va5, va6, va7);
                if (j < NB) {
                    LOADB(va0, va1, va2, va3, va4, va5, va6, va7, j);
                    j += 2;
                    ACCB(vb0, vb1, vb2, vb3, vb4, vb5, vb6, vb7);
                } else {
                    ACCB(vb0, vb1, vb2, vb3, vb4, vb5, vb6, vb7);
                    goto gather_done;
                }
            }
            ACCB(va0, va1, va2, va3, va4, va5, va6, va7);
        }
gather_done: ;
#undef LOADB
#undef ACCB

        const double lacc = ((ac0 + ac1) + (ac2 + ac3)) + ((ac4 + ac5) + (ac6 + ac7));
        if (!isA) s_latB[hp] = lacc;
        __syncthreads();

        // ---- phase 2 (group A): membrane update + spike + build next list ----
        if (isA) {
            const double lat = lacc + s_latB[tid];
            mp = 0.95 * mp + icv - lat;
            if (refrac > 0) mp = 0.0;
            refrac = (refrac > 0) ? (refrac - 1) : 0;
            const bool spike = (mp >= th);
            if (spike) { mp = 0.0; refrac = 2; }

            const uint64_t bm = __ballot(spike);
            const int lane = tid & 63;
            const int cnt = __popcll(bm);
            int base = 0;
            if (lane == 0) {
                mb[(size_t)t * 8 + (tid >> 6)] = bm;  // persist for phase 3
                if (cnt) base = atomicAdd(&s_nact[nxt], cnt);
            }
            base = __shfl(base, 0);
            if (spike) {
                s_act[nxt][base + __popcll(bm & ((1ull << lane) - 1ull))] = tid << 9;  // h*512
            }
        }
        __syncthreads();
        cur = nxt;
    }
}

// ---------------- Phase 3: sparse output GEMM from bitmasks ----------------
__global__ __launch_bounds__(256) void out_gemm(const uint64_t* __restrict__ masks,
                                                const float* __restrict__ wout,
                                                float* __restrict__ out) {
    const int bt = blockIdx.x;
    const int o = threadIdx.x;
    __shared__ uint64_t sm[8];
    if (o < 8) sm[o] = masks[(size_t)bt * 8 + o];
    __syncthreads();

    float acc = 0.0f;
#pragma unroll
    for (int w = 0; w < 8; ++w) {
        uint64_t bits = sm[w];
        while (bits) {
            const int h = (w << 6) + __ffsll((unsigned long long)bits) - 1;
            bits &= bits - 1;
            acc += wout[(size_t)h * OO + o];
        }
    }
    out[(size_t)bt * OO + o] = acc;
}

extern "C" void kernel_launch(void* const* d_in, const int* in_sizes, int n_in,
                              void* d_out, int out_size, void* d_ws, size_t ws_size,
                              hipStream_t stream) {
    const float* x    = (const float*)d_in[0];  // [B, S, I]
    const float* win  = (const float*)d_in[1];  // [I, H]
    const float* wlat = (const float*)d_in[2];  // [H, H]
    const float* wout = (const float*)d_in[3];  // [H, O]
    const float* thr  = (const float*)d_in[4];  // [H]
    float* out = (float*)d_out;                 // [B, S, O]

    // Workspace: ic f64 (128 MB) | masks (2 MB) | wl64 (2.1 MB)
    double* ic = (double*)d_ws;
    char* p = (char*)d_ws + (size_t)BB * SS * HH * sizeof(double);
    uint64_t* masks = (uint64_t*)p;
    p += (size_t)BB * SS * 8 * sizeof(uint64_t);
    double* wl64 = (double*)p;

    const int M = BB * SS;  // 32768
    wlat_to_f64<<<((HH + 1) * HH + 255) / 256, 256, 0, stream>>>(wlat, wl64);
    ic_gemm_f64<<<dim3(M / TM, HH / TN), 256, 0, stream>>>(x, win, ic);
    snn_scan<<<BB, 1024, 0, stream>>>(ic, wl64, thr, masks);
    out_gemm<<<M, 256, 0, stream>>>(masks, wout, out);
}

// Round 5
// 2471.939 us; speedup vs baseline: 2.0514x; 2.0514x over previous
//
#include <hip/hip_runtime.h>
#include <stdint.h>

// Spiking neural network:
//   B=32 batches, S=1024 steps, I=256 inputs, H=512 hidden, O=256 outputs.
// Phase 0: pad wlat (f32) with a 513th all-zero row (enables maskless padding).
// Phase 1: ic[B*S, H] (f64) = x[B*S, I] @ Win[I, H]   (feeds spike decisions)
// Phase 2: sequential scan; 8-chunk dwordx4 gather (f32 loads, f64 accum),
//          LDS partial reduction, 512 neuron owners update + spike.
// Phase 3: out[B*S, O] (f32) = spikes @ Wout via bitmask-driven row sums.
//
// All decision-feeding arithmetic is f64 so spikes match an f64 numpy
// reference exactly; chunk/order nondeterminism only perturbs sums ~1e-15.

#define BB 32
#define SS 1024
#define II 256
#define HH 512
#define OO 256
#define ZEB (HH * HH * 4)   // byte offset of the all-zero row in wpad (1 MB)

// ---------------- Phase 0: wlat -> padded f32 table with zero row ----------------
__global__ __launch_bounds__(256) void wlat_pad(const float* __restrict__ wlat,
                                                float* __restrict__ wpad) {
    const int i = blockIdx.x * 256 + threadIdx.x;
    const int total = (HH + 1) * HH;
    if (i < HH * HH) wpad[i] = wlat[i];
    else if (i < total) wpad[i] = 0.0f;
}

// ---------------- Phase 1: f64-accumulate tiled GEMM ----------------
#define TM 64
#define TN 64
#define TK 16

__global__ __launch_bounds__(256) void ic_gemm_f64(const float* __restrict__ x,
                                                   const float* __restrict__ win,
                                                   double* __restrict__ ic) {
    __shared__ float As[TK][TM + 4];
    __shared__ float Bs[TK][TN];
    const int tid = threadIdx.x;
    const int m0 = blockIdx.x * TM;
    const int n0 = blockIdx.y * TN;
    const int tx = tid & 15;
    const int ty = tid >> 4;

    double acc[4][4];
#pragma unroll
    for (int i = 0; i < 4; ++i)
#pragma unroll
        for (int j = 0; j < 4; ++j) acc[i][j] = 0.0;

    const int lr = tid >> 2;
    const int lq = tid & 3;
    const int br = tid >> 4;
    const int bq = tid & 15;

    for (int k0 = 0; k0 < II; k0 += TK) {
        float4 av = *(const float4*)(x + (size_t)(m0 + lr) * II + k0 + lq * 4);
        float4 bv = *(const float4*)(win + (size_t)(k0 + br) * HH + n0 + bq * 4);
        As[lq * 4 + 0][lr] = av.x;
        As[lq * 4 + 1][lr] = av.y;
        As[lq * 4 + 2][lr] = av.z;
        As[lq * 4 + 3][lr] = av.w;
        *(float4*)(&Bs[br][bq * 4]) = bv;
        __syncthreads();
#pragma unroll
        for (int kk = 0; kk < TK; ++kk) {
            float4 a = *(const float4*)(&As[kk][ty * 4]);
            float4 b = *(const float4*)(&Bs[kk][tx * 4]);
            const double a0 = (double)a.x, a1 = (double)a.y, a2 = (double)a.z, a3 = (double)a.w;
            const double b0 = (double)b.x, b1 = (double)b.y, b2 = (double)b.z, b3 = (double)b.w;
            acc[0][0] += a0 * b0; acc[0][1] += a0 * b1; acc[0][2] += a0 * b2; acc[0][3] += a0 * b3;
            acc[1][0] += a1 * b0; acc[1][1] += a1 * b1; acc[1][2] += a1 * b2; acc[1][3] += a1 * b3;
            acc[2][0] += a2 * b0; acc[2][1] += a2 * b1; acc[2][2] += a2 * b2; acc[2][3] += a2 * b3;
            acc[3][0] += a3 * b0; acc[3][1] += a3 * b1; acc[3][2] += a3 * b2; acc[3][3] += a3 * b3;
        }
        __syncthreads();
    }

#pragma unroll
    for (int i = 0; i < 4; ++i) {
        double* row = ic + (size_t)(m0 + ty * 4 + i) * HH + n0 + tx * 4;
#pragma unroll
        for (int j = 0; j < 4; ++j) row[j] = acc[i][j];
    }
}

// ---------------- Phase 2: sequential scan ----------------
// One block per batch, 1024 threads = 16 waves.
// Gather: thread t -> chunk c = t>>7 (2 waves per chunk), quad q = t&127,
// columns 4q..4q+3. Chunk c processes active-list indices c, c+8, c+16, ...
// (list stores byte offsets h*2048, zero-row padded so over-reads are free
// L1 hits contributing 0.0).
// Reduce: s_part[8][520] f64, slot XOR-swizzle (col ^ ((col>>4)&3)) kills the
// 32B-stride write bank conflict. Threads 0..511 sum 8 partials and update.
__global__ __launch_bounds__(1024) void snn_scan(const double* __restrict__ ic,
                                                 const float* __restrict__ wpad,
                                                 const float* __restrict__ thr,
                                                 uint64_t* __restrict__ masks) {
    __shared__ int s_act[2][544];        // padded active lists (byte offsets)
    __shared__ int s_nact[2];
    __shared__ double s_part[8][520];    // per-chunk partial sums, swizzled slots

    const int tid = threadIdx.x;
    const int b = blockIdx.x;
    const double* icb = ic + (size_t)b * SS * HH;
    uint64_t* mb = masks + (size_t)b * SS * 8;

    const int chunk = tid >> 7;          // 0..7
    const int q = tid & 127;             // column quad
    const int colb = q << 4;             // byte offset of first of 4 columns
    const int sw = (q >> 2) & 3;         // slot swizzle for this thread's quad
    const bool isA = (tid < HH);

    double mp = 0.0;
    int refrac = 0;
    double th = 0.0;
    if (isA) th = (double)thr[tid];
    const int rsw = isA ? (tid ^ ((tid >> 4) & 3)) : 0;  // read slot for column tid
    if (tid == 0) { s_nact[0] = 0; s_nact[1] = 0; }
    if (tid < 544) { s_act[0][tid] = ZEB; s_act[1][tid] = ZEB; }
    __syncthreads();

    int cur = 0;
    for (int t = 0; t < SS; ++t) {
        const int nxt = cur ^ 1;

        // ---- G phase: ic prefetch, housekeeping, chunked gather ----
        double icv = 0.0;
        if (isA) icv = icb[(size_t)t * HH + tid];
        if (tid == 1023) s_nact[nxt] = 0;
        if (tid < 544) s_act[nxt][tid] = ZEB;  // last read 2 barriers ago: safe

        const int n = s_nact[cur];
        const int NB = (n + 7) >> 3;         // elements per chunk (pad-extended)
        const int* act = s_act[cur];

        double ac0 = 0.0, ac1 = 0.0, ac2 = 0.0, ac3 = 0.0;
        {
            int idx = chunk;
            // 3-deep rotation; over-reads land in the L1-hot zero row.
            float4 f0 = *(const float4*)((const char*)wpad + (unsigned)(act[idx] + colb));
            float4 f1 = *(const float4*)((const char*)wpad + (unsigned)(act[idx + 8] + colb));
            for (int k = 0; k < NB; ++k) {
                float4 f2 = *(const float4*)((const char*)wpad + (unsigned)(act[idx + 16] + colb));
                ac0 += (double)f0.x;
                ac1 += (double)f0.y;
                ac2 += (double)f0.z;
                ac3 += (double)f0.w;
                f0 = f1; f1 = f2; idx += 8;
            }
        }
        // write 4 partials to swizzled slots (4q..4q+3 permuted by sw)
        {
            const int base = q << 2;
            s_part[chunk][(base + 0) ^ sw] = ac0;
            s_part[chunk][(base + 1) ^ sw] = ac1;
            s_part[chunk][(base + 2) ^ sw] = ac2;
            s_part[chunk][(base + 3) ^ sw] = ac3;
        }
        __syncthreads();

        // ---- R+U phase (threads 0..511): reduce, update, spike, append ----
        if (isA) {
            double lat = ((s_part[0][rsw] + s_part[1][rsw]) +
                          (s_part[2][rsw] + s_part[3][rsw])) +
                         ((s_part[4][rsw] + s_part[5][rsw]) +
                          (s_part[6][rsw] + s_part[7][rsw]));
            mp = 0.95 * mp + icv - lat;
            if (refrac > 0) mp = 0.0;
            refrac = (refrac > 0) ? (refrac - 1) : 0;
            const bool spike = (mp >= th);
            if (spike) { mp = 0.0; refrac = 2; }

            const uint64_t bm = __ballot(spike);
            const int lane = tid & 63;
            const int cnt = __popcll(bm);
            int base = 0;
            if (lane == 0) {
                mb[(size_t)t * 8 + (tid >> 6)] = bm;  // persist for phase 3
                if (cnt) base = atomicAdd(&s_nact[nxt], cnt);
            }
            base = __shfl(base, 0);
            if (spike) {
                s_act[nxt][base + __popcll(bm & ((1ull << lane) - 1ull))] = tid << 11;  // h*2048 bytes
            }
        }
        __syncthreads();
        cur = nxt;
    }
}

// ---------------- Phase 3: sparse output GEMM from bitmasks ----------------
__global__ __launch_bounds__(256) void out_gemm(const uint64_t* __restrict__ masks,
                                                const float* __restrict__ wout,
                                                float* __restrict__ out) {
    const int bt = blockIdx.x;
    const int o = threadIdx.x;
    __shared__ uint64_t sm[8];
    if (o < 8) sm[o] = masks[(size_t)bt * 8 + o];
    __syncthreads();

    float acc = 0.0f;
#pragma unroll
    for (int w = 0; w < 8; ++w) {
        uint64_t bits = sm[w];
        while (bits) {
            const int h = (w << 6) + __ffsll((unsigned long long)bits) - 1;
            bits &= bits - 1;
            acc += wout[(size_t)h * OO + o];
        }
    }
    out[(size_t)bt * OO + o] = acc;
}

extern "C" void kernel_launch(void* const* d_in, const int* in_sizes, int n_in,
                              void* d_out, int out_size, void* d_ws, size_t ws_size,
                              hipStream_t stream) {
    const float* x    = (const float*)d_in[0];  // [B, S, I]
    const float* win  = (const float*)d_in[1];  // [I, H]
    const float* wlat = (const float*)d_in[2];  // [H, H]
    const float* wout = (const float*)d_in[3];  // [H, O]
    const float* thr  = (const float*)d_in[4];  // [H]
    float* out = (float*)d_out;                 // [B, S, O]

    // Workspace: ic f64 (128 MB) | masks (2 MB) | wpad f32 (1.05 MB)
    double* ic = (double*)d_ws;
    char* p = (char*)d_ws + (size_t)BB * SS * HH * sizeof(double);
    uint64_t* masks = (uint64_t*)p;
    p += (size_t)BB * SS * 8 * sizeof(uint64_t);
    float* wpad = (float*)p;

    const int M = BB * SS;  // 32768
    wlat_pad<<<((HH + 1) * HH + 255) / 256, 256, 0, stream>>>(wlat, wpad);
    ic_gemm_f64<<<dim3(M / TM, HH / TN), 256, 0, stream>>>(x, win, ic);
    snn_scan<<<BB, 1024, 0, stream>>>(ic, wpad, thr, masks);
    out_gemm<<<M, 256, 0, stream>>>(masks, wout, out);
}